// Round 8
// baseline (507.237 us; speedup 1.0000x reference)
//
#include <hip/hip_runtime.h>

typedef unsigned short u16;
typedef short vshort8 __attribute__((ext_vector_type(8)));
typedef __bf16 vbf16x8 __attribute__((ext_vector_type(8)));
typedef float vf32x4 __attribute__((ext_vector_type(4)));
typedef float vf32x16 __attribute__((ext_vector_type(16)));

__device__ __forceinline__ u16 f2bf(float f) {
  unsigned u = __builtin_bit_cast(unsigned, f);
  u += 0x7FFFu + ((u >> 16) & 1u);
  return (u16)(u >> 16);
}

__device__ __forceinline__ unsigned cvtpk(float lo, float hi) {
  unsigned r;
  asm("v_cvt_pk_bf16_f32 %0, %1, %2" : "=v"(r) : "v"(lo), "v"(hi));
  return r;
}

// v_permlane32_swap_b32 D,S: D' = {D.lo32lanes, S.lo32lanes}, S' = {D.hi32lanes, S.hi32lanes}
// (semantics confirmed by round-4 identity-failure signature)
__device__ __forceinline__ void plswap(unsigned& a, unsigned& b) {
  asm("v_permlane32_swap_b32 %0, %1" : "+v"(a), "+v"(b));
}

// y[lane] = x[lane^32]
__device__ __forceinline__ float swap32f(float x) { return __shfl_xor(x, 32); }

__device__ __forceinline__ vf32x4 mfma_bf16(vshort8 a, vshort8 b, vf32x4 c) {
  return __builtin_amdgcn_mfma_f32_16x16x32_bf16(
      __builtin_bit_cast(vbf16x8, a), __builtin_bit_cast(vbf16x8, b), c, 0, 0, 0);
}

__device__ __forceinline__ vf32x16 mfma32(vshort8 a, vshort8 b, vf32x16 c) {
  return __builtin_amdgcn_mfma_f32_32x32x16_bf16(
      __builtin_bit_cast(vbf16x8, a), __builtin_bit_cast(vbf16x8, b), c, 0, 0, 0);
}

__device__ __forceinline__ void gload16(const void* g, void* l) {
  __builtin_amdgcn_global_load_lds(
      (const __attribute__((address_space(1))) void*)g,
      (__attribute__((address_space(3))) void*)l, 16, 0, 0);
}

// ---------------- fp32 -> bf16 elementwise (1 or 2 tensors via blockIdx.y) ----------------
__global__ __launch_bounds__(256) void cvtk2(const float* __restrict__ a,
                                             const float* __restrict__ b,
                                             u16* __restrict__ oa,
                                             u16* __restrict__ ob, int n4) {
  const float* in = blockIdx.y ? b : a;
  u16* out = blockIdx.y ? ob : oa;
  if (in == nullptr) return;
  int idx = blockIdx.x * 256 + threadIdx.x;
  int stride = gridDim.x * 256;
  for (int i = idx; i < n4; i += stride) {
    float4 v = ((const float4*)in)[i];
    unsigned lo = (unsigned)f2bf(v.x) | ((unsigned)f2bf(v.y) << 16);
    unsigned hi = (unsigned)f2bf(v.z) | ((unsigned)f2bf(v.w) << 16);
    uint2 o; o.x = lo; o.y = hi;
    *(uint2*)&out[(size_t)i * 4] = o;
  }
}

// ---------------- weight transpose + cvt: W[k][n] f32 -> Wt[n][k] bf16 (4 via z) ----------------
__global__ __launch_bounds__(256) void wtrans4(const float* __restrict__ w0,
                                               const float* __restrict__ w1,
                                               const float* __restrict__ w2,
                                               const float* __restrict__ w3,
                                               u16* __restrict__ o0, u16* __restrict__ o1,
                                               u16* __restrict__ o2, u16* __restrict__ o3) {
  int z = blockIdx.z;
  const float* W = z == 0 ? w0 : z == 1 ? w1 : z == 2 ? w2 : w3;
  u16* Wt = z == 0 ? o0 : z == 1 ? o1 : z == 2 ? o2 : o3;
  __shared__ u16 tile[64][72];
  int t = threadIdx.x;
  int n0 = blockIdx.x * 64, k0 = blockIdx.y * 64;
#pragma unroll
  for (int it = 0; it < 4; ++it) {
    int cid = it * 256 + t;
    int r = cid >> 4, c4 = cid & 15;
    float4 v = *(const float4*)&W[(k0 + r) * 1024 + n0 + c4 * 4];
    u16* d = &tile[r][c4 * 4];
    d[0] = f2bf(v.x); d[1] = f2bf(v.y); d[2] = f2bf(v.z); d[3] = f2bf(v.w);
  }
  __syncthreads();
#pragma unroll
  for (int it = 0; it < 4; ++it) {
    int cid = it * 256 + t;
    int rn = cid >> 4, c4 = cid & 15;
    unsigned lo = (unsigned)tile[c4 * 4 + 0][rn] | ((unsigned)tile[c4 * 4 + 1][rn] << 16);
    unsigned hi = (unsigned)tile[c4 * 4 + 2][rn] | ((unsigned)tile[c4 * 4 + 3][rn] << 16);
    uint2 o; o.x = lo; o.y = hi;
    *(uint2*)&Wt[(n0 + rn) * 1024 + k0 + c4 * 4] = o;
  }
}

// ---------------- V transpose: V[b*2048+s][h*64+d] -> Vt[(bh*64+d)][s] (bf16) ----------------
__global__ __launch_bounds__(256) void vtrans(const u16* __restrict__ V,
                                              u16* __restrict__ Vt) {
  __shared__ u16 tile[64][72];
  int t = threadIdx.x;
  int s0 = blockIdx.x * 64;
  int bh = blockIdx.y, b = bh >> 4, h = bh & 15;
#pragma unroll
  for (int it = 0; it < 2; ++it) {
    int cid = it * 256 + t;
    int r = cid >> 3, c8 = cid & 7;
    vshort8 v = *(const vshort8*)&V[(size_t)(b * 2048 + s0 + r) * 1024 + h * 64 + c8 * 8];
    *(vshort8*)&tile[r][c8 * 8] = v;
  }
  __syncthreads();
#pragma unroll
  for (int it = 0; it < 2; ++it) {
    int cid = it * 256 + t;
    int rd = cid >> 3, c8 = cid & 7;
    unsigned w[4];
#pragma unroll
    for (int j = 0; j < 4; ++j) {
      unsigned lo = tile[c8 * 8 + 2 * j][rd];
      unsigned hi = tile[c8 * 8 + 2 * j + 1][rd];
      w[j] = lo | (hi << 16);
    }
    uint4 o; o.x = w[0]; o.y = w[1]; o.z = w[2]; o.w = w[3];
    *(uint4*)&Vt[(size_t)(bh * 64 + rd) * 2048 + s0 + c8 * 8] = o;
  }
}

// ---------------- bf16 GEMM core ----------------
template <int OUTF32>
__device__ __forceinline__ void gemm_core(const u16* __restrict__ A,
                                          const u16* __restrict__ Bt,
                                          float* __restrict__ Cf,
                                          u16* __restrict__ Cb,
                                          int M, int N, int K, float oscale) {
  __shared__ __align__(16) u16 As[128 * 64];
  __shared__ __align__(16) u16 Bs[128 * 64];
  int t = threadIdx.x, lane = t & 63, wid = t >> 6;
  int g = lane >> 4, i16 = lane & 15;
  int n0 = blockIdx.x * 128, m0 = blockIdx.y * 128;
  int wm = wid >> 1, wn = wid & 1;

  vf32x4 acc[4][4];
#pragma unroll
  for (int a = 0; a < 4; ++a)
#pragma unroll
    for (int b = 0; b < 4; ++b) acc[a][b] = (vf32x4){0.f, 0.f, 0.f, 0.f};

  int ldsbase = (wid * 64) * 8;
  for (int kt = 0; kt < K / 64; ++kt) {
    if (kt) __syncthreads();
#pragma unroll
    for (int it = 0; it < 4; ++it) {
      int cid = it * 256 + t;
      int row = cid >> 3, c = cid & 7, sc = c ^ (row & 7);
      gload16(A + (size_t)(m0 + row) * K + kt * 64 + sc * 8, &As[it * 2048 + ldsbase]);
    }
#pragma unroll
    for (int it = 0; it < 4; ++it) {
      int cid = it * 256 + t;
      int row = cid >> 3, c = cid & 7, sc = c ^ (row & 7);
      gload16(Bt + (size_t)(n0 + row) * K + kt * 64 + sc * 8, &Bs[it * 2048 + ldsbase]);
    }
    __syncthreads();
#pragma unroll
    for (int kc = 0; kc < 2; ++kc) {
      vshort8 af[4], bf[4];
#pragma unroll
      for (int mf = 0; mf < 4; ++mf) {
        int row = wm * 64 + mf * 16 + i16;
        int ch = (kc * 4 + g) ^ (row & 7);
        af[mf] = *(const vshort8*)&As[row * 64 + ch * 8];
      }
#pragma unroll
      for (int nf = 0; nf < 4; ++nf) {
        int row = wn * 64 + nf * 16 + i16;
        int ch = (kc * 4 + g) ^ (row & 7);
        bf[nf] = *(const vshort8*)&Bs[row * 64 + ch * 8];
      }
#pragma unroll
      for (int mf = 0; mf < 4; ++mf)
#pragma unroll
        for (int nf = 0; nf < 4; ++nf)
          acc[mf][nf] = mfma_bf16(af[mf], bf[nf], acc[mf][nf]);
    }
  }
#pragma unroll
  for (int mf = 0; mf < 4; ++mf)
#pragma unroll
    for (int nf = 0; nf < 4; ++nf)
#pragma unroll
      for (int r = 0; r < 4; ++r) {
        int m = m0 + wm * 64 + mf * 16 + g * 4 + r;
        int n = n0 + wn * 64 + nf * 16 + i16;
        if (OUTF32)
          Cf[(size_t)m * N + n] = acc[mf][nf][r] * oscale;
        else
          Cb[(size_t)m * N + n] = f2bf(acc[mf][nf][r] * oscale);
      }
}

template <int OUTF32>
__global__ __launch_bounds__(256) void gemm_nt(const u16* __restrict__ A,
                                               const u16* __restrict__ Bt,
                                               float* __restrict__ Cf,
                                               u16* __restrict__ Cb,
                                               int M, int N, int K, float oscale) {
  gemm_core<OUTF32>(A, Bt, Cf, Cb, M, N, K, oscale);
}

// two independent bf16->bf16 GEMMs in one launch (z selects)
__global__ __launch_bounds__(256) void gemm_nt2(const u16* __restrict__ A0,
                                                const u16* __restrict__ B0,
                                                u16* __restrict__ C0, float os0,
                                                const u16* __restrict__ A1,
                                                const u16* __restrict__ B1,
                                                u16* __restrict__ C1, float os1,
                                                int M, int N, int K) {
  if (blockIdx.z == 0)
    gemm_core<0>(A0, B0, nullptr, C0, M, N, K, os0);
  else
    gemm_core<0>(A1, B1, nullptr, C1, M, N, K, os1);
}

// ---------------- fused flash attention: 64 q-rows/wave, zero LDS, K double-buffered ----------------
// Fixed-shift softmax (no online max: P = exp2(S) un-normalized, exact by shift-invariance),
// permlane32_swap P-redistribution.
// Q (pre-scaled by 0.125*log2e), K: [8192,1024] bf16; Vt: [64*64,2048] bf16; O: [8192,1024] bf16
__device__ __forceinline__ void attn_body(int kt, const u16* __restrict__ Kbase,
                                          const u16* __restrict__ Vbase,
                                          vshort8 (&kfc)[2][4], vshort8 (&kfn)[2][4],
                                          vshort8 (&qf)[2][4], vf32x16 (&oacc)[2][2],
                                          float (&lrun)[2], int l31, int hi) {
  int ktn = kt + 1 < 32 ? kt + 1 : 31;
  // prefetch next K tile (consumed next body)
#pragma unroll
  for (int ks = 0; ks < 2; ++ks)
#pragma unroll
    for (int dc = 0; dc < 4; ++dc)
      kfn[ks][dc] = *(const vshort8*)&Kbase[(size_t)(ktn * 64 + ks * 32 + l31) * 1024 + dc * 16 + hi * 8];

  unsigned pk[2][2][8];
#pragma unroll
  for (int fq = 0; fq < 2; ++fq) {
    // S^T = K·Q for this q-half
    vf32x16 sacc[2];
#pragma unroll
    for (int ks = 0; ks < 2; ++ks)
#pragma unroll
      for (int r = 0; r < 16; ++r) sacc[ks][r] = 0.f;
    __builtin_amdgcn_s_setprio(1);
#pragma unroll
    for (int dc = 0; dc < 4; ++dc)
#pragma unroll
      for (int ks = 0; ks < 2; ++ks)
        sacc[ks] = mfma32(kfc[ks][dc], qf[fq][dc], sacc[ks]);
    __builtin_amdgcn_s_setprio(0);

    // un-normalized exp2 + pack + per-lane partial sum (no max pass)
    float s0 = 0.f, s1 = 0.f, s2 = 0.f, s3 = 0.f;
#pragma unroll
    for (int ks = 0; ks < 2; ++ks)
#pragma unroll
      for (int u = 0; u < 8; ++u) {
        float p0 = exp2f(sacc[ks][2 * u]);
        float p1 = exp2f(sacc[ks][2 * u + 1]);
        pk[fq][ks][u] = cvtpk(p0, p1);
        if (u & 1) { s0 += p0; s1 += p1; } else { s2 += p0; s3 += p1; }
      }
    lrun[fq] += (s0 + s1) + (s2 + s3);
  }

  // V^T fragments for current tile
  vshort8 vtf[2][4];
#pragma unroll
  for (int dm = 0; dm < 2; ++dm)
#pragma unroll
    for (int s = 0; s < 4; ++s)
      vtf[dm][s] = *(const vshort8*)&Vbase[(size_t)(dm * 32 + l31) * 2048 + kt * 64 + s * 16 + hi * 8];

  // in-register P redistribution via permlane32_swap + PV
#pragma unroll
  for (int s = 0; s < 4; ++s) {
    vshort8 pb[2];
    const int ks = s >> 1, s1b = s & 1;
#pragma unroll
    for (int fq = 0; fq < 2; ++fq) {
      unsigned x0 = pk[fq][ks][4 * s1b + 0], x1 = pk[fq][ks][4 * s1b + 1];
      unsigned y0 = pk[fq][ks][4 * s1b + 2], y1 = pk[fq][ks][4 * s1b + 3];
      plswap(x0, y0);  // x0 = {A0.lo,B0.lo}, y0 = {A0.hi,B0.hi}
      plswap(x1, y1);
      uint4 wv; wv.x = x0; wv.y = x1; wv.z = y0; wv.w = y1;
      pb[fq] = __builtin_bit_cast(vshort8, wv);
    }
    __builtin_amdgcn_s_setprio(1);
#pragma unroll
    for (int dm = 0; dm < 2; ++dm)
#pragma unroll
      for (int fq = 0; fq < 2; ++fq)
        oacc[dm][fq] = mfma32(vtf[dm][s], pb[fq], oacc[dm][fq]);
    __builtin_amdgcn_s_setprio(0);
  }
}

__global__ __launch_bounds__(512, 2) void attn_fwd7(const u16* __restrict__ Q,
                                                    const u16* __restrict__ K,
                                                    const u16* __restrict__ Vt,
                                                    u16* __restrict__ O) {
  int t = threadIdx.x, lane = t & 63, w = t >> 6;
  int l31 = lane & 31, hi = lane >> 5;
  int i = blockIdx.x;                    // 256 blocks
  int qb = (i >> 3) & 3;
  int bh = (i & 7) + 8 * (i >> 5);       // same-bh blocks share XCD
  int b = bh >> 4, h = bh & 15;

  const u16* Qbase = Q + (size_t)(b * 2048 + qb * 512 + w * 64) * 1024 + h * 64;
  const u16* Kbase = K + (size_t)(b * 2048) * 1024 + h * 64;
  const u16* Vbase = Vt + (size_t)(bh * 64) * 2048;

  vshort8 qf[2][4];
#pragma unroll
  for (int fq = 0; fq < 2; ++fq)
#pragma unroll
    for (int dc = 0; dc < 4; ++dc)
      qf[fq][dc] = *(const vshort8*)&Qbase[(size_t)(fq * 32 + l31) * 1024 + dc * 16 + hi * 8];

  vf32x16 oacc[2][2];
#pragma unroll
  for (int dm = 0; dm < 2; ++dm)
#pragma unroll
    for (int fq = 0; fq < 2; ++fq)
#pragma unroll
      for (int r = 0; r < 16; ++r) oacc[dm][fq][r] = 0.f;
  float lrun[2] = {0.f, 0.f};

  // initial K tile
  vshort8 kfA[2][4], kfB[2][4];
#pragma unroll
  for (int ks = 0; ks < 2; ++ks)
#pragma unroll
    for (int dc = 0; dc < 4; ++dc)
      kfA[ks][dc] = *(const vshort8*)&Kbase[(size_t)(ks * 32 + l31) * 1024 + dc * 16 + hi * 8];

  for (int kt = 0; kt < 32; kt += 2) {
    attn_body(kt,     Kbase, Vbase, kfA, kfB, qf, oacc, lrun, l31, hi);
    attn_body(kt + 1, Kbase, Vbase, kfB, kfA, qf, oacc, lrun, l31, hi);
  }

  // epilogue: cross-half sum of lrun, normalize, store
#pragma unroll
  for (int fq = 0; fq < 2; ++fq) {
    float lt = lrun[fq] + swap32f(lrun[fq]);
    float inv = 1.f / lt;
    size_t qrow = (size_t)(b * 2048 + qb * 512 + w * 64 + fq * 32 + l31);
#pragma unroll
    for (int dm = 0; dm < 2; ++dm)
#pragma unroll
      for (int u = 0; u < 4; ++u) {
        unsigned w0 = cvtpk(oacc[dm][fq][4 * u + 0] * inv, oacc[dm][fq][4 * u + 1] * inv);
        unsigned w1 = cvtpk(oacc[dm][fq][4 * u + 2] * inv, oacc[dm][fq][4 * u + 3] * inv);
        uint2 o; o.x = w0; o.y = w1;
        *(uint2*)&O[qrow * 1024 + h * 64 + dm * 32 + 8 * u + 4 * hi] = o;
      }
  }
}

extern "C" void kernel_launch(void* const* d_in, const int* in_sizes, int n_in,
                              void* d_out, int out_size, void* d_ws, size_t ws_size,
                              hipStream_t stream) {
  const float* q  = (const float*)d_in[0];
  const float* k  = (const float*)d_in[1];
  const float* v  = (const float*)d_in[2];
  const float* wq = (const float*)d_in[3];
  const float* wk = (const float*)d_in[4];
  const float* wv = (const float*)d_in[5];
  const float* wo = (const float*)d_in[6];
  float* out = (float*)d_out;

  const int M = 8192, D = 1024;
  u16* Qb = (u16*)d_out;                // Q,K (bf16) parked in d_out (32MB)
  u16* Kb = Qb + (size_t)M * D;
  u16* xb  = (u16*)d_ws;                // staging / attn-out
  u16* Vb  = xb + (size_t)M * D;
  u16* Vtg = Vb + (size_t)M * D;        // doubles as xk staging before vtrans
  u16* wqt = Vtg + (size_t)M * D;
  u16* wkt = wqt + (size_t)D * D;
  u16* wvt = wkt + (size_t)D * D;
  u16* wot = wvt + (size_t)D * D;

  dim3 blk(256);
  wtrans4<<<dim3(16, 16, 4), blk, 0, stream>>>(wq, wk, wv, wo, wqt, wkt, wvt, wot);

  const float QSCALE = 0.125f * 1.44269504088896f;  // 1/sqrt(64) * log2(e)
  int n4 = M * D / 4;
  cvtk2<<<dim3(1024, 2), blk, 0, stream>>>(q, k, xb, Vtg, n4);
  gemm_nt2<<<dim3(8, 64, 2), blk, 0, stream>>>(xb, wqt, Qb, QSCALE,
                                               Vtg, wkt, Kb, 1.0f, M, D, D);
  cvtk2<<<dim3(1024, 1), blk, 0, stream>>>(v, nullptr, xb, nullptr, n4);
  gemm_nt<0><<<dim3(8, 64), blk, 0, stream>>>(xb, wvt, nullptr, Vb, M, D, D, 1.0f);

  vtrans<<<dim3(32, 64), blk, 0, stream>>>(Vb, Vtg);
  attn_fwd7<<<dim3(256), dim3(512), 0, stream>>>(Qb, Kb, Vtg, xb /* -> attn out */);
  gemm_nt<1><<<dim3(8, 64), blk, 0, stream>>>(xb, wot, out, nullptr, M, D, D, 1.0f);
}

// Round 9
// 274.885 us; speedup vs baseline: 1.8453x; 1.8453x over previous
//
#include <hip/hip_runtime.h>

typedef unsigned short u16;
typedef short vshort8 __attribute__((ext_vector_type(8)));
typedef __bf16 vbf16x8 __attribute__((ext_vector_type(8)));
typedef float vf32x4 __attribute__((ext_vector_type(4)));
typedef float vf32x16 __attribute__((ext_vector_type(16)));

__device__ __forceinline__ u16 f2bf(float f) {
  unsigned u = __builtin_bit_cast(unsigned, f);
  u += 0x7FFFu + ((u >> 16) & 1u);
  return (u16)(u >> 16);
}

__device__ __forceinline__ unsigned cvtpk(float lo, float hi) {
  unsigned r;
  asm("v_cvt_pk_bf16_f32 %0, %1, %2" : "=v"(r) : "v"(lo), "v"(hi));
  return r;
}

// y[lane] = x[lane^32]
__device__ __forceinline__ float swap32f(float x) { return __shfl_xor(x, 32); }

__device__ __forceinline__ vf32x4 mfma_bf16(vshort8 a, vshort8 b, vf32x4 c) {
  return __builtin_amdgcn_mfma_f32_16x16x32_bf16(
      __builtin_bit_cast(vbf16x8, a), __builtin_bit_cast(vbf16x8, b), c, 0, 0, 0);
}

__device__ __forceinline__ vf32x16 mfma32(vshort8 a, vshort8 b, vf32x16 c) {
  return __builtin_amdgcn_mfma_f32_32x32x16_bf16(
      __builtin_bit_cast(vbf16x8, a), __builtin_bit_cast(vbf16x8, b), c, 0, 0, 0);
}

__device__ __forceinline__ void gload16(const void* g, void* l) {
  __builtin_amdgcn_global_load_lds(
      (const __attribute__((address_space(1))) void*)g,
      (__attribute__((address_space(3))) void*)l, 16, 0, 0);
}

// ---------------- fp32 -> bf16 elementwise (1 or 2 tensors via blockIdx.y) ----------------
__global__ __launch_bounds__(256) void cvtk2(const float* __restrict__ a,
                                             const float* __restrict__ b,
                                             u16* __restrict__ oa,
                                             u16* __restrict__ ob, int n4) {
  const float* in = blockIdx.y ? b : a;
  u16* out = blockIdx.y ? ob : oa;
  if (in == nullptr) return;
  int idx = blockIdx.x * 256 + threadIdx.x;
  int stride = gridDim.x * 256;
  for (int i = idx; i < n4; i += stride) {
    float4 v = ((const float4*)in)[i];
    unsigned lo = (unsigned)f2bf(v.x) | ((unsigned)f2bf(v.y) << 16);
    unsigned hi = (unsigned)f2bf(v.z) | ((unsigned)f2bf(v.w) << 16);
    uint2 o; o.x = lo; o.y = hi;
    *(uint2*)&out[(size_t)i * 4] = o;
  }
}

// ---------------- weight transpose + cvt: W[k][n] f32 -> Wt[n][k] bf16 (4 via z) ----------------
__global__ __launch_bounds__(256) void wtrans4(const float* __restrict__ w0,
                                               const float* __restrict__ w1,
                                               const float* __restrict__ w2,
                                               const float* __restrict__ w3,
                                               u16* __restrict__ o0, u16* __restrict__ o1,
                                               u16* __restrict__ o2, u16* __restrict__ o3) {
  int z = blockIdx.z;
  const float* W = z == 0 ? w0 : z == 1 ? w1 : z == 2 ? w2 : w3;
  u16* Wt = z == 0 ? o0 : z == 1 ? o1 : z == 2 ? o2 : o3;
  __shared__ u16 tile[64][72];
  int t = threadIdx.x;
  int n0 = blockIdx.x * 64, k0 = blockIdx.y * 64;
#pragma unroll
  for (int it = 0; it < 4; ++it) {
    int cid = it * 256 + t;
    int r = cid >> 4, c4 = cid & 15;
    float4 v = *(const float4*)&W[(k0 + r) * 1024 + n0 + c4 * 4];
    u16* d = &tile[r][c4 * 4];
    d[0] = f2bf(v.x); d[1] = f2bf(v.y); d[2] = f2bf(v.z); d[3] = f2bf(v.w);
  }
  __syncthreads();
#pragma unroll
  for (int it = 0; it < 4; ++it) {
    int cid = it * 256 + t;
    int rn = cid >> 4, c4 = cid & 15;
    unsigned lo = (unsigned)tile[c4 * 4 + 0][rn] | ((unsigned)tile[c4 * 4 + 1][rn] << 16);
    unsigned hi = (unsigned)tile[c4 * 4 + 2][rn] | ((unsigned)tile[c4 * 4 + 3][rn] << 16);
    uint2 o; o.x = lo; o.y = hi;
    *(uint2*)&Wt[(n0 + rn) * 1024 + k0 + c4 * 4] = o;
  }
}

// ---------------- V transpose: V[b*2048+s][h*64+d] -> Vt[(bh*64+d)][s] (bf16) ----------------
__global__ __launch_bounds__(256) void vtrans(const u16* __restrict__ V,
                                              u16* __restrict__ Vt) {
  __shared__ u16 tile[64][72];
  int t = threadIdx.x;
  int s0 = blockIdx.x * 64;
  int bh = blockIdx.y, b = bh >> 4, h = bh & 15;
#pragma unroll
  for (int it = 0; it < 2; ++it) {
    int cid = it * 256 + t;
    int r = cid >> 3, c8 = cid & 7;
    vshort8 v = *(const vshort8*)&V[(size_t)(b * 2048 + s0 + r) * 1024 + h * 64 + c8 * 8];
    *(vshort8*)&tile[r][c8 * 8] = v;
  }
  __syncthreads();
#pragma unroll
  for (int it = 0; it < 2; ++it) {
    int cid = it * 256 + t;
    int rd = cid >> 3, c8 = cid & 7;
    unsigned w[4];
#pragma unroll
    for (int j = 0; j < 4; ++j) {
      unsigned lo = tile[c8 * 8 + 2 * j][rd];
      unsigned hi = tile[c8 * 8 + 2 * j + 1][rd];
      w[j] = lo | (hi << 16);
    }
    uint4 o; o.x = w[0]; o.y = w[1]; o.z = w[2]; o.w = w[3];
    *(uint4*)&Vt[(size_t)(bh * 64 + rd) * 2048 + s0 + c8 * 8] = o;
  }
}

// ---------------- bf16 GEMM core ----------------
template <int OUTF32>
__device__ __forceinline__ void gemm_core(const u16* __restrict__ A,
                                          const u16* __restrict__ Bt,
                                          float* __restrict__ Cf,
                                          u16* __restrict__ Cb,
                                          int M, int N, int K, float oscale) {
  __shared__ __align__(16) u16 As[128 * 64];
  __shared__ __align__(16) u16 Bs[128 * 64];
  int t = threadIdx.x, lane = t & 63, wid = t >> 6;
  int g = lane >> 4, i16 = lane & 15;
  int n0 = blockIdx.x * 128, m0 = blockIdx.y * 128;
  int wm = wid >> 1, wn = wid & 1;

  vf32x4 acc[4][4];
#pragma unroll
  for (int a = 0; a < 4; ++a)
#pragma unroll
    for (int b = 0; b < 4; ++b) acc[a][b] = (vf32x4){0.f, 0.f, 0.f, 0.f};

  int ldsbase = (wid * 64) * 8;
  for (int kt = 0; kt < K / 64; ++kt) {
    if (kt) __syncthreads();
#pragma unroll
    for (int it = 0; it < 4; ++it) {
      int cid = it * 256 + t;
      int row = cid >> 3, c = cid & 7, sc = c ^ (row & 7);
      gload16(A + (size_t)(m0 + row) * K + kt * 64 + sc * 8, &As[it * 2048 + ldsbase]);
    }
#pragma unroll
    for (int it = 0; it < 4; ++it) {
      int cid = it * 256 + t;
      int row = cid >> 3, c = cid & 7, sc = c ^ (row & 7);
      gload16(Bt + (size_t)(n0 + row) * K + kt * 64 + sc * 8, &Bs[it * 2048 + ldsbase]);
    }
    __syncthreads();
#pragma unroll
    for (int kc = 0; kc < 2; ++kc) {
      vshort8 af[4], bf[4];
#pragma unroll
      for (int mf = 0; mf < 4; ++mf) {
        int row = wm * 64 + mf * 16 + i16;
        int ch = (kc * 4 + g) ^ (row & 7);
        af[mf] = *(const vshort8*)&As[row * 64 + ch * 8];
      }
#pragma unroll
      for (int nf = 0; nf < 4; ++nf) {
        int row = wn * 64 + nf * 16 + i16;
        int ch = (kc * 4 + g) ^ (row & 7);
        bf[nf] = *(const vshort8*)&Bs[row * 64 + ch * 8];
      }
#pragma unroll
      for (int mf = 0; mf < 4; ++mf)
#pragma unroll
        for (int nf = 0; nf < 4; ++nf)
          acc[mf][nf] = mfma_bf16(af[mf], bf[nf], acc[mf][nf]);
    }
  }
#pragma unroll
  for (int mf = 0; mf < 4; ++mf)
#pragma unroll
    for (int nf = 0; nf < 4; ++nf)
#pragma unroll
      for (int r = 0; r < 4; ++r) {
        int m = m0 + wm * 64 + mf * 16 + g * 4 + r;
        int n = n0 + wn * 64 + nf * 16 + i16;
        if (OUTF32)
          Cf[(size_t)m * N + n] = acc[mf][nf][r] * oscale;
        else
          Cb[(size_t)m * N + n] = f2bf(acc[mf][nf][r] * oscale);
      }
}

template <int OUTF32>
__global__ __launch_bounds__(256) void gemm_nt(const u16* __restrict__ A,
                                               const u16* __restrict__ Bt,
                                               float* __restrict__ Cf,
                                               u16* __restrict__ Cb,
                                               int M, int N, int K, float oscale) {
  gemm_core<OUTF32>(A, Bt, Cf, Cb, M, N, K, oscale);
}

// two independent bf16->bf16 GEMMs in one launch (z selects)
__global__ __launch_bounds__(256) void gemm_nt2(const u16* __restrict__ A0,
                                                const u16* __restrict__ B0,
                                                u16* __restrict__ C0, float os0,
                                                const u16* __restrict__ A1,
                                                const u16* __restrict__ B1,
                                                u16* __restrict__ C1, float os1,
                                                int M, int N, int K) {
  if (blockIdx.z == 0)
    gemm_core<0>(A0, B0, nullptr, C0, M, N, K, os0);
  else
    gemm_core<0>(A1, B1, nullptr, C1, M, N, K, os1);
}

// ---------------- fused flash attention: k-split x2, 64 q-rows/wave, K double-buffered ----------------
// Per-wave body identical to the proven round-5 attn_fwd4 (online max, shfl_xor redistribution).
// Block = 512 threads = 8 waves = 4 q-groups x 2 k-halves; LDS merge at the end.
// Q (pre-scaled by 0.125*log2e), K: [8192,1024] bf16; Vt: [64*64,2048] bf16; O: [8192,1024] bf16
__device__ __forceinline__ void attn_body(int kt, int ktmax, const u16* __restrict__ Kbase,
                                          const u16* __restrict__ Vbase,
                                          vshort8 (&kfc)[2][4], vshort8 (&kfn)[2][4],
                                          vshort8 (&qf)[2][4], vf32x16 (&oacc)[2][2],
                                          float (&mrun)[2], float (&lrun)[2],
                                          int l31, int hi) {
  int ktn = kt + 1 < ktmax ? kt + 1 : ktmax - 1;
  // prefetch next K tile (consumed next body; latency hidden under this body's chain)
#pragma unroll
  for (int ks = 0; ks < 2; ++ks)
#pragma unroll
    for (int dc = 0; dc < 4; ++dc)
      kfn[ks][dc] = *(const vshort8*)&Kbase[(size_t)(ktn * 64 + ks * 32 + l31) * 1024 + dc * 16 + hi * 8];

  unsigned pk[2][2][8];
#pragma unroll
  for (int fq = 0; fq < 2; ++fq) {
    // S^T = K·Q for this q-half
    vf32x16 sacc[2];
#pragma unroll
    for (int ks = 0; ks < 2; ++ks)
#pragma unroll
      for (int r = 0; r < 16; ++r) sacc[ks][r] = 0.f;
    __builtin_amdgcn_s_setprio(1);
#pragma unroll
    for (int dc = 0; dc < 4; ++dc)
#pragma unroll
      for (int ks = 0; ks < 2; ++ks)
        sacc[ks] = mfma32(kfc[ks][dc], qf[fq][dc], sacc[ks]);
    __builtin_amdgcn_s_setprio(0);

    // tree max over the 32 in-lane values + one cross-half swap
    float tm[8];
#pragma unroll
    for (int r = 0; r < 8; ++r)
      tm[r] = fmaxf(fmaxf(sacc[0][r], sacc[0][r + 8]), fmaxf(sacc[1][r], sacc[1][r + 8]));
#pragma unroll
    for (int r = 0; r < 4; ++r) tm[r] = fmaxf(tm[r], tm[r + 4]);
    float pmax = fmaxf(fmaxf(tm[0], tm[1]), fmaxf(tm[2], tm[3]));
    pmax = fmaxf(pmax, swap32f(pmax));

    if (pmax > mrun[fq] + 8.f) {  // defer-max
      float al = exp2f(mrun[fq] - pmax);
      lrun[fq] *= al;
#pragma unroll
      for (int dm = 0; dm < 2; ++dm)
#pragma unroll
        for (int r = 0; r < 16; ++r) oacc[dm][fq][r] *= al;
      mrun[fq] = pmax;
    }
    float mm = mrun[fq];

    // exp2 + pack + per-lane partial sum (cross-half sum deferred to merge)
    float s0 = 0.f, s1 = 0.f, s2 = 0.f, s3 = 0.f;
#pragma unroll
    for (int ks = 0; ks < 2; ++ks)
#pragma unroll
      for (int u = 0; u < 8; ++u) {
        float p0 = exp2f(sacc[ks][2 * u] - mm);
        float p1 = exp2f(sacc[ks][2 * u + 1] - mm);
        pk[fq][ks][u] = cvtpk(p0, p1);
        if (u & 1) { s0 += p0; s1 += p1; } else { s2 += p0; s3 += p1; }
      }
    lrun[fq] += (s0 + s1) + (s2 + s3);
  }

  // V^T fragments for current tile
  vshort8 vtf[2][4];
#pragma unroll
  for (int dm = 0; dm < 2; ++dm)
#pragma unroll
    for (int s = 0; s < 4; ++s)
      vtf[dm][s] = *(const vshort8*)&Vbase[(size_t)(dm * 32 + l31) * 2048 + kt * 64 + s * 16 + hi * 8];

  // in-register P redistribution + PV
#pragma unroll
  for (int s = 0; s < 4; ++s) {
    vshort8 pb[2];
    const int ks = s >> 1, s1b = s & 1;
#pragma unroll
    for (int fq = 0; fq < 2; ++fq) {
      unsigned wA0 = pk[fq][ks][4 * s1b + 0], wA1 = pk[fq][ks][4 * s1b + 1];
      unsigned wB0 = pk[fq][ks][4 * s1b + 2], wB1 = pk[fq][ks][4 * s1b + 3];
      unsigned sA0 = hi ? wB0 : wA0, sA1 = hi ? wB1 : wA1;
      unsigned sd0 = hi ? wA0 : wB0, sd1 = hi ? wA1 : wB1;
      unsigned rv0 = __shfl_xor((int)sd0, 32), rv1 = __shfl_xor((int)sd1, 32);
      uint4 wv;
      wv.x = hi ? rv0 : sA0; wv.y = hi ? rv1 : sA1;
      wv.z = hi ? sA0 : rv0; wv.w = hi ? sA1 : rv1;
      pb[fq] = __builtin_bit_cast(vshort8, wv);
    }
    __builtin_amdgcn_s_setprio(1);
#pragma unroll
    for (int dm = 0; dm < 2; ++dm)
#pragma unroll
      for (int fq = 0; fq < 2; ++fq)
        oacc[dm][fq] = mfma32(vtf[dm][s], pb[fq], oacc[dm][fq]);
    __builtin_amdgcn_s_setprio(0);
  }
}

__global__ __launch_bounds__(512, 2) void attn_fwd8(const u16* __restrict__ Q,
                                                    const u16* __restrict__ K,
                                                    const u16* __restrict__ Vt,
                                                    u16* __restrict__ O) {
  __shared__ float2 sm_ml[8][2][64];   // [wave][fq][lane] {m,l}  (8 KB)
  __shared__ float sm_o[4][64][64];    // [qg][reg][lane]         (64 KB)

  int t = threadIdx.x, lane = t & 63, w = t >> 6;
  int l31 = lane & 31, hi = lane >> 5;
  int qg = w >> 1, kh = w & 1;
  int i = blockIdx.x;                    // 512 blocks
  int bh = (i & 7) + 8 * (i >> 6);       // same-bh blocks share XCD
  int qc = (i >> 3) & 7;                 // 8 q-chunks of 256 rows
  int b = bh >> 4, h = bh & 15;

  const u16* Qbase = Q + (size_t)(b * 2048 + qc * 256 + qg * 64) * 1024 + h * 64;
  const u16* Kbase = K + (size_t)(b * 2048 + kh * 1024) * 1024 + h * 64;
  const u16* Vbase = Vt + (size_t)(bh * 64) * 2048 + kh * 1024;

  vshort8 qf[2][4];
#pragma unroll
  for (int fq = 0; fq < 2; ++fq)
#pragma unroll
    for (int dc = 0; dc < 4; ++dc)
      qf[fq][dc] = *(const vshort8*)&Qbase[(size_t)(fq * 32 + l31) * 1024 + dc * 16 + hi * 8];

  vf32x16 oacc[2][2];
#pragma unroll
  for (int dm = 0; dm < 2; ++dm)
#pragma unroll
    for (int fq = 0; fq < 2; ++fq)
#pragma unroll
      for (int r = 0; r < 16; ++r) oacc[dm][fq][r] = 0.f;
  float mrun[2] = {-3.0e38f, -3.0e38f}, lrun[2] = {0.f, 0.f};

  // initial K tile
  vshort8 kfA[2][4], kfB[2][4];
#pragma unroll
  for (int ks = 0; ks < 2; ++ks)
#pragma unroll
    for (int dc = 0; dc < 4; ++dc)
      kfA[ks][dc] = *(const vshort8*)&Kbase[(size_t)(ks * 32 + l31) * 1024 + dc * 16 + hi * 8];

  for (int kt = 0; kt < 16; kt += 2) {
    attn_body(kt,     16, Kbase, Vbase, kfA, kfB, qf, oacc, mrun, lrun, l31, hi);
    attn_body(kt + 1, 16, Kbase, Vbase, kfB, kfA, qf, oacc, mrun, lrun, l31, hi);
  }

  // ---------- pair merge (kh=0 wave combines with kh=1 wave of same qg) ----------
  sm_ml[w][0][lane] = make_float2(mrun[0], lrun[0]);
  sm_ml[w][1][lane] = make_float2(mrun[1], lrun[1]);
  __syncthreads();
  float fs[2], flt[2];
#pragma unroll
  for (int fq = 0; fq < 2; ++fq) {
    float2 p = sm_ml[w ^ 1][fq][lane];
    float ms = fmaxf(mrun[fq], p.x);
    fs[fq] = exp2f(mrun[fq] - ms);
    float fp = exp2f(p.x - ms);
    flt[fq] = lrun[fq] * fs[fq] + p.y * fp;  // combined per-lane l
  }
  if (kh == 1) {
#pragma unroll
    for (int dm = 0; dm < 2; ++dm)
#pragma unroll
      for (int fq = 0; fq < 2; ++fq)
#pragma unroll
        for (int r = 0; r < 16; ++r)
          sm_o[qg][dm * 32 + fq * 16 + r][lane] = oacc[dm][fq][r] * fs[fq];
  }
  __syncthreads();
  if (kh == 0) {
#pragma unroll
    for (int fq = 0; fq < 2; ++fq) {
      float lt = flt[fq] + swap32f(flt[fq]);
      float inv = 1.f / lt;
      size_t qrow = (size_t)(b * 2048 + qc * 256 + qg * 64 + fq * 32 + l31);
#pragma unroll
      for (int dm = 0; dm < 2; ++dm)
#pragma unroll
        for (int u = 0; u < 4; ++u) {
          float c0 = oacc[dm][fq][4 * u + 0] * fs[fq] + sm_o[qg][dm * 32 + fq * 16 + 4 * u + 0][lane];
          float c1 = oacc[dm][fq][4 * u + 1] * fs[fq] + sm_o[qg][dm * 32 + fq * 16 + 4 * u + 1][lane];
          float c2 = oacc[dm][fq][4 * u + 2] * fs[fq] + sm_o[qg][dm * 32 + fq * 16 + 4 * u + 2][lane];
          float c3 = oacc[dm][fq][4 * u + 3] * fs[fq] + sm_o[qg][dm * 32 + fq * 16 + 4 * u + 3][lane];
          unsigned w0 = cvtpk(c0 * inv, c1 * inv);
          unsigned w1 = cvtpk(c2 * inv, c3 * inv);
          uint2 o; o.x = w0; o.y = w1;
          *(uint2*)&O[qrow * 1024 + h * 64 + dm * 32 + 8 * u + 4 * hi] = o;
        }
    }
  }
}

extern "C" void kernel_launch(void* const* d_in, const int* in_sizes, int n_in,
                              void* d_out, int out_size, void* d_ws, size_t ws_size,
                              hipStream_t stream) {
  const float* q  = (const float*)d_in[0];
  const float* k  = (const float*)d_in[1];
  const float* v  = (const float*)d_in[2];
  const float* wq = (const float*)d_in[3];
  const float* wk = (const float*)d_in[4];
  const float* wv = (const float*)d_in[5];
  const float* wo = (const float*)d_in[6];
  float* out = (float*)d_out;

  const int M = 8192, D = 1024;
  u16* Qb = (u16*)d_out;                // Q,K (bf16) parked in d_out (32MB)
  u16* Kb = Qb + (size_t)M * D;
  u16* xb  = (u16*)d_ws;                // staging / attn-out
  u16* Vb  = xb + (size_t)M * D;
  u16* Vtg = Vb + (size_t)M * D;        // doubles as xk staging before vtrans
  u16* wqt = Vtg + (size_t)M * D;
  u16* wkt = wqt + (size_t)D * D;
  u16* wvt = wkt + (size_t)D * D;
  u16* wot = wvt + (size_t)D * D;

  dim3 blk(256);
  wtrans4<<<dim3(16, 16, 4), blk, 0, stream>>>(wq, wk, wv, wo, wqt, wkt, wvt, wot);

  const float QSCALE = 0.125f * 1.44269504088896f;  // 1/sqrt(64) * log2(e)
  int n4 = M * D / 4;
  cvtk2<<<dim3(1024, 2), blk, 0, stream>>>(q, k, xb, Vtg, n4);
  gemm_nt2<<<dim3(8, 64, 2), blk, 0, stream>>>(xb, wqt, Qb, QSCALE,
                                               Vtg, wkt, Kb, 1.0f, M, D, D);
  cvtk2<<<dim3(1024, 1), blk, 0, stream>>>(v, nullptr, xb, nullptr, n4);
  gemm_nt<0><<<dim3(8, 64), blk, 0, stream>>>(xb, wvt, nullptr, Vb, M, D, D, 1.0f);

  vtrans<<<dim3(32, 64), blk, 0, stream>>>(Vb, Vtg);
  attn_fwd8<<<dim3(512), dim3(512), 0, stream>>>(Qb, Kb, Vtg, xb /* -> attn out */);
  gemm_nt<1><<<dim3(8, 64), blk, 0, stream>>>(xb, wot, out, nullptr, M, D, D, 1.0f);
}

// Round 10
// 265.803 us; speedup vs baseline: 1.9083x; 1.0342x over previous
//
#include <hip/hip_runtime.h>

typedef unsigned short u16;
typedef short vshort8 __attribute__((ext_vector_type(8)));
typedef __bf16 vbf16x8 __attribute__((ext_vector_type(8)));
typedef float vf32x4 __attribute__((ext_vector_type(4)));
typedef float vf32x16 __attribute__((ext_vector_type(16)));

__device__ __forceinline__ u16 f2bf(float f) {
  unsigned u = __builtin_bit_cast(unsigned, f);
  u += 0x7FFFu + ((u >> 16) & 1u);
  return (u16)(u >> 16);
}

__device__ __forceinline__ unsigned cvtpk(float lo, float hi) {
  unsigned r;
  asm("v_cvt_pk_bf16_f32 %0, %1, %2" : "=v"(r) : "v"(lo), "v"(hi));
  return r;
}

// v_permlane32_swap_b32 a,b: a' = {a.lo32lanes, b.lo32lanes}, b' = {a.hi32lanes, b.hi32lanes}
// correctness-validated in round 8 (kernel passed with this mapping)
__device__ __forceinline__ void plswap(unsigned& a, unsigned& b) {
  asm("v_permlane32_swap_b32 %0, %1" : "+v"(a), "+v"(b));
}

// y[lane] = x[lane^32]
__device__ __forceinline__ float swap32f(float x) { return __shfl_xor(x, 32); }

__device__ __forceinline__ vf32x4 mfma_bf16(vshort8 a, vshort8 b, vf32x4 c) {
  return __builtin_amdgcn_mfma_f32_16x16x32_bf16(
      __builtin_bit_cast(vbf16x8, a), __builtin_bit_cast(vbf16x8, b), c, 0, 0, 0);
}

__device__ __forceinline__ vf32x16 mfma32(vshort8 a, vshort8 b, vf32x16 c) {
  return __builtin_amdgcn_mfma_f32_32x32x16_bf16(
      __builtin_bit_cast(vbf16x8, a), __builtin_bit_cast(vbf16x8, b), c, 0, 0, 0);
}

__device__ __forceinline__ void gload16(const void* g, void* l) {
  __builtin_amdgcn_global_load_lds(
      (const __attribute__((address_space(1))) void*)g,
      (__attribute__((address_space(3))) void*)l, 16, 0, 0);
}

// ---------------- fp32 -> bf16 elementwise (1 or 2 tensors via blockIdx.y) ----------------
__global__ __launch_bounds__(256) void cvtk2(const float* __restrict__ a,
                                             const float* __restrict__ b,
                                             u16* __restrict__ oa,
                                             u16* __restrict__ ob, int n4) {
  const float* in = blockIdx.y ? b : a;
  u16* out = blockIdx.y ? ob : oa;
  if (in == nullptr) return;
  int idx = blockIdx.x * 256 + threadIdx.x;
  int stride = gridDim.x * 256;
  for (int i = idx; i < n4; i += stride) {
    float4 v = ((const float4*)in)[i];
    unsigned lo = (unsigned)f2bf(v.x) | ((unsigned)f2bf(v.y) << 16);
    unsigned hi = (unsigned)f2bf(v.z) | ((unsigned)f2bf(v.w) << 16);
    uint2 o; o.x = lo; o.y = hi;
    *(uint2*)&out[(size_t)i * 4] = o;
  }
}

// ---------------- weight transpose + cvt: W[k][n] f32 -> Wt[n][k] bf16 (4 via z) ----------------
__global__ __launch_bounds__(256) void wtrans4(const float* __restrict__ w0,
                                               const float* __restrict__ w1,
                                               const float* __restrict__ w2,
                                               const float* __restrict__ w3,
                                               u16* __restrict__ o0, u16* __restrict__ o1,
                                               u16* __restrict__ o2, u16* __restrict__ o3) {
  int z = blockIdx.z;
  const float* W = z == 0 ? w0 : z == 1 ? w1 : z == 2 ? w2 : w3;
  u16* Wt = z == 0 ? o0 : z == 1 ? o1 : z == 2 ? o2 : o3;
  __shared__ u16 tile[64][72];
  int t = threadIdx.x;
  int n0 = blockIdx.x * 64, k0 = blockIdx.y * 64;
#pragma unroll
  for (int it = 0; it < 4; ++it) {
    int cid = it * 256 + t;
    int r = cid >> 4, c4 = cid & 15;
    float4 v = *(const float4*)&W[(k0 + r) * 1024 + n0 + c4 * 4];
    u16* d = &tile[r][c4 * 4];
    d[0] = f2bf(v.x); d[1] = f2bf(v.y); d[2] = f2bf(v.z); d[3] = f2bf(v.w);
  }
  __syncthreads();
#pragma unroll
  for (int it = 0; it < 4; ++it) {
    int cid = it * 256 + t;
    int rn = cid >> 4, c4 = cid & 15;
    unsigned lo = (unsigned)tile[c4 * 4 + 0][rn] | ((unsigned)tile[c4 * 4 + 1][rn] << 16);
    unsigned hi = (unsigned)tile[c4 * 4 + 2][rn] | ((unsigned)tile[c4 * 4 + 3][rn] << 16);
    uint2 o; o.x = lo; o.y = hi;
    *(uint2*)&Wt[(n0 + rn) * 1024 + k0 + c4 * 4] = o;
  }
}

// ---------------- V transpose: V[b*2048+s][h*64+d] -> Vt[(bh*64+d)][s] (bf16) ----------------
__global__ __launch_bounds__(256) void vtrans(const u16* __restrict__ V,
                                              u16* __restrict__ Vt) {
  __shared__ u16 tile[64][72];
  int t = threadIdx.x;
  int s0 = blockIdx.x * 64;
  int bh = blockIdx.y, b = bh >> 4, h = bh & 15;
#pragma unroll
  for (int it = 0; it < 2; ++it) {
    int cid = it * 256 + t;
    int r = cid >> 3, c8 = cid & 7;
    vshort8 v = *(const vshort8*)&V[(size_t)(b * 2048 + s0 + r) * 1024 + h * 64 + c8 * 8];
    *(vshort8*)&tile[r][c8 * 8] = v;
  }
  __syncthreads();
#pragma unroll
  for (int it = 0; it < 2; ++it) {
    int cid = it * 256 + t;
    int rd = cid >> 3, c8 = cid & 7;
    unsigned w[4];
#pragma unroll
    for (int j = 0; j < 4; ++j) {
      unsigned lo = tile[c8 * 8 + 2 * j][rd];
      unsigned hi = tile[c8 * 8 + 2 * j + 1][rd];
      w[j] = lo | (hi << 16);
    }
    uint4 o; o.x = w[0]; o.y = w[1]; o.z = w[2]; o.w = w[3];
    *(uint4*)&Vt[(size_t)(bh * 64 + rd) * 2048 + s0 + c8 * 8] = o;
  }
}

// ---------------- bf16 GEMM core ----------------
template <int OUTF32>
__device__ __forceinline__ void gemm_core(const u16* __restrict__ A,
                                          const u16* __restrict__ Bt,
                                          float* __restrict__ Cf,
                                          u16* __restrict__ Cb,
                                          int M, int N, int K, float oscale) {
  __shared__ __align__(16) u16 As[128 * 64];
  __shared__ __align__(16) u16 Bs[128 * 64];
  int t = threadIdx.x, lane = t & 63, wid = t >> 6;
  int g = lane >> 4, i16 = lane & 15;
  int n0 = blockIdx.x * 128, m0 = blockIdx.y * 128;
  int wm = wid >> 1, wn = wid & 1;

  vf32x4 acc[4][4];
#pragma unroll
  for (int a = 0; a < 4; ++a)
#pragma unroll
    for (int b = 0; b < 4; ++b) acc[a][b] = (vf32x4){0.f, 0.f, 0.f, 0.f};

  int ldsbase = (wid * 64) * 8;
  for (int kt = 0; kt < K / 64; ++kt) {
    if (kt) __syncthreads();
#pragma unroll
    for (int it = 0; it < 4; ++it) {
      int cid = it * 256 + t;
      int row = cid >> 3, c = cid & 7, sc = c ^ (row & 7);
      gload16(A + (size_t)(m0 + row) * K + kt * 64 + sc * 8, &As[it * 2048 + ldsbase]);
    }
#pragma unroll
    for (int it = 0; it < 4; ++it) {
      int cid = it * 256 + t;
      int row = cid >> 3, c = cid & 7, sc = c ^ (row & 7);
      gload16(Bt + (size_t)(n0 + row) * K + kt * 64 + sc * 8, &Bs[it * 2048 + ldsbase]);
    }
    __syncthreads();
#pragma unroll
    for (int kc = 0; kc < 2; ++kc) {
      vshort8 af[4], bf[4];
#pragma unroll
      for (int mf = 0; mf < 4; ++mf) {
        int row = wm * 64 + mf * 16 + i16;
        int ch = (kc * 4 + g) ^ (row & 7);
        af[mf] = *(const vshort8*)&As[row * 64 + ch * 8];
      }
#pragma unroll
      for (int nf = 0; nf < 4; ++nf) {
        int row = wn * 64 + nf * 16 + i16;
        int ch = (kc * 4 + g) ^ (row & 7);
        bf[nf] = *(const vshort8*)&Bs[row * 64 + ch * 8];
      }
#pragma unroll
      for (int mf = 0; mf < 4; ++mf)
#pragma unroll
        for (int nf = 0; nf < 4; ++nf)
          acc[mf][nf] = mfma_bf16(af[mf], bf[nf], acc[mf][nf]);
    }
  }
#pragma unroll
  for (int mf = 0; mf < 4; ++mf)
#pragma unroll
    for (int nf = 0; nf < 4; ++nf)
#pragma unroll
      for (int r = 0; r < 4; ++r) {
        int m = m0 + wm * 64 + mf * 16 + g * 4 + r;
        int n = n0 + wn * 64 + nf * 16 + i16;
        if (OUTF32)
          Cf[(size_t)m * N + n] = acc[mf][nf][r] * oscale;
        else
          Cb[(size_t)m * N + n] = f2bf(acc[mf][nf][r] * oscale);
      }
}

template <int OUTF32>
__global__ __launch_bounds__(256) void gemm_nt(const u16* __restrict__ A,
                                               const u16* __restrict__ Bt,
                                               float* __restrict__ Cf,
                                               u16* __restrict__ Cb,
                                               int M, int N, int K, float oscale) {
  gemm_core<OUTF32>(A, Bt, Cf, Cb, M, N, K, oscale);
}

// two independent bf16->bf16 GEMMs in one launch (z selects)
__global__ __launch_bounds__(256) void gemm_nt2(const u16* __restrict__ A0,
                                                const u16* __restrict__ B0,
                                                u16* __restrict__ C0, float os0,
                                                const u16* __restrict__ A1,
                                                const u16* __restrict__ B1,
                                                u16* __restrict__ C1, float os1,
                                                int M, int N, int K) {
  if (blockIdx.z == 0)
    gemm_core<0>(A0, B0, nullptr, C0, M, N, K, os0);
  else
    gemm_core<0>(A1, B1, nullptr, C1, M, N, K, os1);
}

// ---------------- fused flash attention: 64 q-rows/wave, zero LDS, K double-buffered ----------------
// Round-5 structure (146us proven) + permlane32_swap P-redistribution (round-8-validated).
// Online max retained: numerics + acts as the liveness fence separating the two fq chains.
// Q (pre-scaled by 0.125*log2e), K: [8192,1024] bf16; Vt: [64*64,2048] bf16; O: [8192,1024] bf16
__device__ __forceinline__ void attn_body(int kt, const u16* __restrict__ Kbase,
                                          const u16* __restrict__ Vbase,
                                          vshort8 (&kfc)[2][4], vshort8 (&kfn)[2][4],
                                          vshort8 (&qf)[2][4], vf32x16 (&oacc)[2][2],
                                          float (&mrun)[2], float (&lrun)[2],
                                          int l31, int hi) {
  int ktn = kt + 1 < 32 ? kt + 1 : 31;
  // prefetch next K tile (consumed next body; latency hidden under this body's chain)
#pragma unroll
  for (int ks = 0; ks < 2; ++ks)
#pragma unroll
    for (int dc = 0; dc < 4; ++dc)
      kfn[ks][dc] = *(const vshort8*)&Kbase[(size_t)(ktn * 64 + ks * 32 + l31) * 1024 + dc * 16 + hi * 8];

  unsigned pk[2][2][8];
#pragma unroll
  for (int fq = 0; fq < 2; ++fq) {
    // S^T = K·Q for this q-half
    vf32x16 sacc[2];
#pragma unroll
    for (int ks = 0; ks < 2; ++ks)
#pragma unroll
      for (int r = 0; r < 16; ++r) sacc[ks][r] = 0.f;
    __builtin_amdgcn_s_setprio(1);
#pragma unroll
    for (int dc = 0; dc < 4; ++dc)
#pragma unroll
      for (int ks = 0; ks < 2; ++ks)
        sacc[ks] = mfma32(kfc[ks][dc], qf[fq][dc], sacc[ks]);
    __builtin_amdgcn_s_setprio(0);

    // tree max over the 32 in-lane values + one cross-half swap
    float tm[8];
#pragma unroll
    for (int r = 0; r < 8; ++r)
      tm[r] = fmaxf(fmaxf(sacc[0][r], sacc[0][r + 8]), fmaxf(sacc[1][r], sacc[1][r + 8]));
#pragma unroll
    for (int r = 0; r < 4; ++r) tm[r] = fmaxf(tm[r], tm[r + 4]);
    float pmax = fmaxf(fmaxf(tm[0], tm[1]), fmaxf(tm[2], tm[3]));
    pmax = fmaxf(pmax, swap32f(pmax));

    if (pmax > mrun[fq] + 8.f) {  // defer-max
      float al = exp2f(mrun[fq] - pmax);
      lrun[fq] *= al;
#pragma unroll
      for (int dm = 0; dm < 2; ++dm)
#pragma unroll
        for (int r = 0; r < 16; ++r) oacc[dm][fq][r] *= al;
      mrun[fq] = pmax;
    }
    float mm = mrun[fq];

    // exp2 + pack + per-lane partial sum (cross-half sum deferred to epilogue)
    float s0 = 0.f, s1 = 0.f, s2 = 0.f, s3 = 0.f;
#pragma unroll
    for (int ks = 0; ks < 2; ++ks)
#pragma unroll
      for (int u = 0; u < 8; ++u) {
        float p0 = exp2f(sacc[ks][2 * u] - mm);
        float p1 = exp2f(sacc[ks][2 * u + 1] - mm);
        pk[fq][ks][u] = cvtpk(p0, p1);
        if (u & 1) { s0 += p0; s1 += p1; } else { s2 += p0; s3 += p1; }
      }
    lrun[fq] += (s0 + s1) + (s2 + s3);
  }

  // V^T fragments for current tile
  vshort8 vtf[2][4];
#pragma unroll
  for (int dm = 0; dm < 2; ++dm)
#pragma unroll
    for (int s = 0; s < 4; ++s)
      vtf[dm][s] = *(const vshort8*)&Vbase[(size_t)(dm * 32 + l31) * 2048 + kt * 64 + s * 16 + hi * 8];

  // in-register P redistribution via permlane32_swap + PV
#pragma unroll
  for (int s = 0; s < 4; ++s) {
    vshort8 pb[2];
    const int ks = s >> 1, s1b = s & 1;
#pragma unroll
    for (int fq = 0; fq < 2; ++fq) {
      unsigned x0 = pk[fq][ks][4 * s1b + 0], x1 = pk[fq][ks][4 * s1b + 1];
      unsigned y0 = pk[fq][ks][4 * s1b + 2], y1 = pk[fq][ks][4 * s1b + 3];
      plswap(x0, y0);  // x0 = {A.lo,B.lo}, y0 = {A.hi,B.hi}
      plswap(x1, y1);
      uint4 wv; wv.x = x0; wv.y = x1; wv.z = y0; wv.w = y1;
      pb[fq] = __builtin_bit_cast(vshort8, wv);
    }
    __builtin_amdgcn_s_setprio(1);
#pragma unroll
    for (int dm = 0; dm < 2; ++dm)
#pragma unroll
      for (int fq = 0; fq < 2; ++fq)
        oacc[dm][fq] = mfma32(vtf[dm][s], pb[fq], oacc[dm][fq]);
    __builtin_amdgcn_s_setprio(0);
  }
}

__global__ __launch_bounds__(512, 2) void attn_fwd9(const u16* __restrict__ Q,
                                                    const u16* __restrict__ K,
                                                    const u16* __restrict__ Vt,
                                                    u16* __restrict__ O) {
  int t = threadIdx.x, lane = t & 63, w = t >> 6;
  int l31 = lane & 31, hi = lane >> 5;
  int i = blockIdx.x;                    // 256 blocks
  int qb = (i >> 3) & 3;
  int bh = (i & 7) + 8 * (i >> 5);       // same-bh blocks share XCD
  int b = bh >> 4, h = bh & 15;

  const u16* Qbase = Q + (size_t)(b * 2048 + qb * 512 + w * 64) * 1024 + h * 64;
  const u16* Kbase = K + (size_t)(b * 2048) * 1024 + h * 64;
  const u16* Vbase = Vt + (size_t)(bh * 64) * 2048;

  vshort8 qf[2][4];
#pragma unroll
  for (int fq = 0; fq < 2; ++fq)
#pragma unroll
    for (int dc = 0; dc < 4; ++dc)
      qf[fq][dc] = *(const vshort8*)&Qbase[(size_t)(fq * 32 + l31) * 1024 + dc * 16 + hi * 8];

  vf32x16 oacc[2][2];
#pragma unroll
  for (int dm = 0; dm < 2; ++dm)
#pragma unroll
    for (int fq = 0; fq < 2; ++fq)
#pragma unroll
      for (int r = 0; r < 16; ++r) oacc[dm][fq][r] = 0.f;
  float mrun[2] = {-3.0e38f, -3.0e38f}, lrun[2] = {0.f, 0.f};

  // initial K tile
  vshort8 kfA[2][4], kfB[2][4];
#pragma unroll
  for (int ks = 0; ks < 2; ++ks)
#pragma unroll
    for (int dc = 0; dc < 4; ++dc)
      kfA[ks][dc] = *(const vshort8*)&Kbase[(size_t)(ks * 32 + l31) * 1024 + dc * 16 + hi * 8];

  for (int kt = 0; kt < 32; kt += 2) {
    attn_body(kt,     Kbase, Vbase, kfA, kfB, qf, oacc, mrun, lrun, l31, hi);
    attn_body(kt + 1, Kbase, Vbase, kfB, kfA, qf, oacc, mrun, lrun, l31, hi);
  }

  // epilogue: cross-half sum of lrun, normalize, store
#pragma unroll
  for (int fq = 0; fq < 2; ++fq) {
    float lt = lrun[fq] + swap32f(lrun[fq]);
    float inv = 1.f / lt;
    size_t qrow = (size_t)(b * 2048 + qb * 512 + w * 64 + fq * 32 + l31);
#pragma unroll
    for (int dm = 0; dm < 2; ++dm)
#pragma unroll
      for (int u = 0; u < 4; ++u) {
        unsigned w0 = cvtpk(oacc[dm][fq][4 * u + 0] * inv, oacc[dm][fq][4 * u + 1] * inv);
        unsigned w1 = cvtpk(oacc[dm][fq][4 * u + 2] * inv, oacc[dm][fq][4 * u + 3] * inv);
        uint2 o; o.x = w0; o.y = w1;
        *(uint2*)&O[qrow * 1024 + h * 64 + dm * 32 + 8 * u + 4 * hi] = o;
      }
  }
}

extern "C" void kernel_launch(void* const* d_in, const int* in_sizes, int n_in,
                              void* d_out, int out_size, void* d_ws, size_t ws_size,
                              hipStream_t stream) {
  const float* q  = (const float*)d_in[0];
  const float* k  = (const float*)d_in[1];
  const float* v  = (const float*)d_in[2];
  const float* wq = (const float*)d_in[3];
  const float* wk = (const float*)d_in[4];
  const float* wv = (const float*)d_in[5];
  const float* wo = (const float*)d_in[6];
  float* out = (float*)d_out;

  const int M = 8192, D = 1024;
  u16* Qb = (u16*)d_out;                // Q,K (bf16) parked in d_out (32MB)
  u16* Kb = Qb + (size_t)M * D;
  u16* xb  = (u16*)d_ws;                // staging / attn-out
  u16* Vb  = xb + (size_t)M * D;
  u16* Vtg = Vb + (size_t)M * D;        // doubles as xk staging before vtrans
  u16* wqt = Vtg + (size_t)M * D;
  u16* wkt = wqt + (size_t)D * D;
  u16* wvt = wkt + (size_t)D * D;
  u16* wot = wvt + (size_t)D * D;

  dim3 blk(256);
  wtrans4<<<dim3(16, 16, 4), blk, 0, stream>>>(wq, wk, wv, wo, wqt, wkt, wvt, wot);

  const float QSCALE = 0.125f * 1.44269504088896f;  // 1/sqrt(64) * log2(e)
  int n4 = M * D / 4;
  cvtk2<<<dim3(1024, 2), blk, 0, stream>>>(q, k, xb, Vtg, n4);
  gemm_nt2<<<dim3(8, 64, 2), blk, 0, stream>>>(xb, wqt, Qb, QSCALE,
                                               Vtg, wkt, Kb, 1.0f, M, D, D);
  cvtk2<<<dim3(1024, 1), blk, 0, stream>>>(v, nullptr, xb, nullptr, n4);
  gemm_nt<0><<<dim3(8, 64), blk, 0, stream>>>(xb, wvt, nullptr, Vb, M, D, D, 1.0f);

  vtrans<<<dim3(32, 64), blk, 0, stream>>>(Vb, Vtg);
  attn_fwd9<<<dim3(256), dim3(512), 0, stream>>>(Qb, Kb, Vtg, xb /* -> attn out */);
  gemm_nt<1><<<dim3(8, 64), blk, 0, stream>>>(xb, wot, out, nullptr, M, D, D, 1.0f);
}